// Round 21
// baseline (71.603 us; speedup 1.0000x reference)
//
#include <hip/hip_runtime.h>
#include <cmath>

#define B_ 8
#define S_ 512
#define D_ 512
#define H_ 1024
#define E_ 8
#define NT_ (B_*S_)   // 4096 tokens
#define TM 16         // tokens per tile (fallback path)
#define MAXTILE 40    // tiles per expert (capacity 1280 tokens/expert)

typedef __attribute__((ext_vector_type(8))) short short8v;
typedef __attribute__((ext_vector_type(4))) float f32x4;

__device__ inline unsigned short f2bf(float f) {
    union { float f; unsigned u; } a; a.f = f;
    unsigned u = a.u;
    return (unsigned short)((u + 0x7FFF + ((u >> 16) & 1)) >> 16);  // RNE
}
__device__ inline float bf2f(unsigned short u) {
    union { unsigned u; float f; } a; a.u = ((unsigned)u) << 16; return a.f;
}

// ======================= TIER A (main path) =======================

// ---- prep_fused ----
// blocks 0..1023   : xbf = bf16(x), per-token gating (no atomics; out NOT written)
// blocks 1024..1535: W1 repack; 1536..2047: W2 repack (4 chunks/wave).
__global__ __launch_bounds__(256) void prep_fused(
    const float* __restrict__ x, const int* __restrict__ mask,
    const float* __restrict__ wg,
    const float* __restrict__ W1, const float* __restrict__ W2,
    unsigned short* __restrict__ xbf,
    uchar2* __restrict__ tokE, float2* __restrict__ tokG,
    unsigned short* __restrict__ W1S, unsigned short* __restrict__ W2S)
{
    const int tid = threadIdx.x, wave = tid >> 6, lane = tid & 63;
    const int bid = blockIdx.x;

    if (bid < 1024) {
        const int t = bid * 4 + wave;
        const float4* xr = (const float4*)(x + ((size_t)t << 9));
        const float4 v0 = xr[lane];
        const float4 v1 = xr[lane + 64];
        union { unsigned short u[4]; uint2 w; } pa, pb;
        pa.u[0]=f2bf(v0.x); pa.u[1]=f2bf(v0.y); pa.u[2]=f2bf(v0.z); pa.u[3]=f2bf(v0.w);
        pb.u[0]=f2bf(v1.x); pb.u[1]=f2bf(v1.y); pb.u[2]=f2bf(v1.z); pb.u[3]=f2bf(v1.w);
        uint2* xrow = (uint2*)(xbf + ((size_t)t << 9));
        xrow[lane] = pa.w; xrow[lane + 64] = pb.w;

        float acc[E_];
#pragma unroll
        for (int e = 0; e < E_; ++e) acc[e] = 0.f;
        const int d0 = lane * 4;
#pragma unroll
        for (int dd = 0; dd < 4; ++dd) {
            const float xa = (&v0.x)[dd], xb = (&v1.x)[dd];
            const float4 wa0 = *(const float4*)(wg + (size_t)(d0 + dd) * 8);
            const float4 wa1 = *(const float4*)(wg + (size_t)(d0 + dd) * 8 + 4);
            const float4 wb0 = *(const float4*)(wg + (size_t)(256 + d0 + dd) * 8);
            const float4 wb1 = *(const float4*)(wg + (size_t)(256 + d0 + dd) * 8 + 4);
            acc[0] += xa * wa0.x + xb * wb0.x;
            acc[1] += xa * wa0.y + xb * wb0.y;
            acc[2] += xa * wa0.z + xb * wb0.z;
            acc[3] += xa * wa0.w + xb * wb0.w;
            acc[4] += xa * wa1.x + xb * wb1.x;
            acc[5] += xa * wa1.y + xb * wb1.y;
            acc[6] += xa * wa1.z + xb * wb1.z;
            acc[7] += xa * wa1.w + xb * wb1.w;
        }
#pragma unroll
        for (int e = 0; e < E_; ++e) {
            float v = acc[e];
#pragma unroll
            for (int off = 32; off > 0; off >>= 1) v += __shfl_xor(v, off, 64);
            acc[e] = v;
        }
        if (lane == 0) {
            if (mask[t] != 0) {
                int i0 = 0; float v0m = acc[0];
#pragma unroll
                for (int e = 1; e < E_; ++e) if (acc[e] > v0m) { v0m = acc[e]; i0 = e; }
                int i1 = -1; float v1m = -INFINITY;
#pragma unroll
                for (int e = 0; e < E_; ++e) if (e != i0 && acc[e] > v1m) { v1m = acc[e]; i1 = e; }
                const float ex = __expf(v1m - v0m);
                const float denom = 1.f + ex;
                tokE[t] = make_uchar2((unsigned char)i0, (unsigned char)i1);
                tokG[t] = make_float2(1.f / denom, ex / denom);
            } else {
                tokE[t] = make_uchar2(255, 255);
            }
        }
        return;
    }

    // -------- direct repack: one wave -> four 1KB chunks (64 cols) --------
    const int isW2 = (bid >= 1536);
    const int q = ((bid - (isW2 ? 1536 : 1024)) << 2) | wave;   // 0..2047
    const int e = q >> 8, rem = q & 255;
    const int g = lane >> 4, m = lane & 15;
    const float* base; unsigned short* dstB; int stride, K32, Fq, kidx;
    if (!isW2) {
        Fq = rem >> 4; kidx = rem & 15;
        stride = H_; K32 = 16; base = W1; dstB = W1S;
    } else {
        Fq = rem >> 5; kidx = rem & 31;
        stride = D_; K32 = 32; base = W2; dstB = W2S;
    }
    const int k = kidx * 32 + g * 8;
    const float* src = base + ((size_t)e << 19) + (size_t)k * stride + Fq * 64 + m;
    float v[4][8];
#pragma unroll
    for (int j = 0; j < 8; ++j) {
#pragma unroll
        for (int c = 0; c < 4; ++c)
            v[c][j] = src[(size_t)j * stride + c * 16];
    }
#pragma unroll
    for (int c = 0; c < 4; ++c) {
        union { unsigned short u[8]; uint4 qv; } p;
#pragma unroll
        for (int j = 0; j < 8; ++j) p.u[j] = f2bf(v[c][j]);
        unsigned short* dst = dstB + ((size_t)e << 19)
                            + ((size_t)((Fq * 4 + c) * K32 + kidx) << 9) + lane * 8;
        *(uint4*)dst = p.qv;
    }
}

// ---- build1: 16 blocks x 256 thr, one token each ----
__global__ __launch_bounds__(256) void build1_kernel(
    const uchar2* __restrict__ tokE,
    ushort2* __restrict__ locs, int* __restrict__ blockCnt)
{
    __shared__ int waveTot[4][E_];
    const int tid = threadIdx.x, lane = tid & 63, wave = tid >> 6;
    const int t = blockIdx.x * 256 + tid;
    const uchar2 ee = tokE[t];
    int scan_pre[E_];
#pragma unroll
    for (int e = 0; e < E_; ++e) {
        const int orig = (ee.x == e) + (ee.y == e);
        int v = orig;
#pragma unroll
        for (int off = 1; off < 64; off <<= 1) {
            const int o = __shfl_up(v, off, 64);
            if (lane >= off) v += o;
        }
        scan_pre[e] = v - orig;
        if (lane == 63) waveTot[wave][e] = v;
    }
    __syncthreads();
    int loc0 = 0, loc1 = 0;
#pragma unroll
    for (int e = 0; e < E_; ++e) {
        int add = 0;
#pragma unroll
        for (int w = 0; w < 4; ++w) if (w < wave) add += waveTot[w][e];
        const int pre = scan_pre[e] + add;
        if (ee.x == e) loc0 = pre;
        if (ee.y == e) loc1 = pre;
    }
    if (tid < E_)
        blockCnt[blockIdx.x * E_ + tid] =
            waveTot[0][tid] + waveTot[1][tid] + waveTot[2][tid] + waveTot[3][tid];
    if (ee.x != 255)
        locs[t] = make_ushort2((unsigned short)loc0, (unsigned short)loc1);
}

// ---- build2: scatter lists (within-expert) + tokSlot (GLOBAL slot) ----
__global__ __launch_bounds__(256) void build2_kernel(
    const uchar2* __restrict__ tokE, const float2* __restrict__ tokG,
    const ushort2* __restrict__ locs, const int* __restrict__ blockCnt,
    int* __restrict__ counts, int* __restrict__ lists, float* __restrict__ gvals,
    ushort2* __restrict__ tokSlot)
{
    __shared__ int bc[16][E_];
    const int tid = threadIdx.x;
    const int b = blockIdx.x;
    if (tid < 16 * E_) bc[tid >> 3][tid & 7] = blockCnt[tid];
    __syncthreads();
    if (b == 0 && tid < E_) {
        int s = 0;
#pragma unroll
        for (int bb = 0; bb < 16; ++bb) s += bc[bb][tid];
        counts[tid] = s;
    }
    const int t = b * 256 + tid;
    const uchar2 ee = tokE[t];
    if (ee.x == 255) return;
    int base0 = 0, base1 = 0, ex0 = 0, ex1 = 0, cum = 0;
#pragma unroll
    for (int e = 0; e < E_; ++e) {
        int boff = 0, tot = 0;
#pragma unroll
        for (int bb = 0; bb < 16; ++bb) {
            const int v = bc[bb][e];
            tot += v;
            if (bb < b) boff += v;
        }
        if (ee.x == e) { base0 = boff; ex0 = cum; }
        if (ee.y == e) { base1 = boff; ex1 = cum; }
        cum += tot;
    }
    const ushort2 lc = locs[t];
    const float2 gg = tokG[t];
    const int s0 = ee.x * NT_ + base0 + lc.x;
    const int s1 = ee.y * NT_ + base1 + lc.y;
    lists[s0] = t; gvals[s0] = gg.x;
    lists[s1] = t; gvals[s1] = gg.y;
    tokSlot[t] = make_ushort2((unsigned short)(ex0 + base0 + lc.x),
                              (unsigned short)(ex1 + base1 + lc.y));
}

// ---- stage1: H[slot][h] = relu(Xbf[tok] @ W1 + b1); X tile in LDS ----
// SWAPPED MFMA; col-split 2 (512 cols/block, 8 frags/wave): X tile staged
// 2x instead of 4x. bid: e=bid&7, nb=(bid>>3)&1, ti=bid>>4; grid=MAXTILE*2*8.
__global__ __launch_bounds__(256) void stage1_kernel(
    const unsigned short* __restrict__ xbf,
    const unsigned short* __restrict__ W1S, const float* __restrict__ b1,
    const int* __restrict__ counts, const int* __restrict__ lists,
    unsigned short* __restrict__ Hbuf)
{
    __shared__ int tks[32];
    __shared__ unsigned short Xs[32 * D_];   // 32 KB
    char* XsC = (char*)Xs;

    const int bid = blockIdx.x;
    const int e  = bid & 7;
    const int nb = (bid >> 3) & 1;
    const int ti = bid >> 4;
    const int n_e = counts[e];
    const int t0 = ti << 5;
    if (t0 >= n_e) return;
    int off = 0;
#pragma unroll
    for (int i = 0; i < E_; ++i) if (i < e) off += counts[i];
    const int mact = min(32, n_e - t0);
    const int tid = threadIdx.x;
    if (tid < 32) tks[tid] = lists[e * NT_ + t0 + min(tid, mact - 1)];
    __syncthreads();

    // stage X tile: 2048 16B chunks, 8 per thread; row reads fully coalesced
#pragma unroll
    for (int j = 0; j < 8; ++j) {
        const int idx = tid + j * 256;       // 0..2047
        const int row = idx >> 6, c = idx & 63;
        const uint4 v = *(const uint4*)(xbf + ((size_t)tks[row] << 9) + c * 8);
        *(uint4*)(XsC + ((row * 1024 + c * 16) ^ ((row & 7) << 4))) = v;
    }
    __syncthreads();

    const int wave = tid >> 6, lane = tid & 63, m = lane & 15, g = lane >> 4;
    const int colbase = nb * 512 + wave * 128;

    const int aoff0 = m * 1024 + (g << 4);
    const int aoff1 = (16 + m) * 1024 + (g << 4);
    const int aswz  = (m & 7) << 4;
    const unsigned short* Bb = W1S + ((size_t)e << 19)
                             + ((size_t)(nb * 32 + wave * 8) << 13) + (lane << 3);

    f32x4 acc[2][8];
#pragma unroll
    for (int i = 0; i < 2; ++i)
#pragma unroll
        for (int f = 0; f < 8; ++f) acc[i][f] = (f32x4){0.f, 0.f, 0.f, 0.f};

#pragma unroll 2
    for (int kk = 0; kk < 16; ++kk) {
        const short8v a0 = *(const short8v*)(XsC + ((aoff0 + (kk << 6)) ^ aswz));
        const short8v a1 = *(const short8v*)(XsC + ((aoff1 + (kk << 6)) ^ aswz));
#pragma unroll
        for (int f = 0; f < 8; ++f) {
            const short8v b = *(const short8v*)(Bb + ((size_t)f << 13) + (kk << 9));
            acc[0][f] = __builtin_amdgcn_mfma_f32_16x16x32_bf16(b, a0, acc[0][f], 0, 0, 0);
            acc[1][f] = __builtin_amdgcn_mfma_f32_16x16x32_bf16(b, a1, acc[1][f], 0, 0, 0);
        }
    }

    // epilogue: lane (g,m) holds h-cols c0..c0+3 of token i*16+m; 8B stores
#pragma unroll
    for (int f = 0; f < 8; ++f) {
        const int c0 = colbase + f * 16 + 4 * g;
        const float4 bv = *(const float4*)(b1 + (e << 10) + c0);
#pragma unroll
        for (int i = 0; i < 2; ++i) {
            const int token = i * 16 + m;
            if (token < mact) {
                const unsigned lo = (unsigned)f2bf(fmaxf(acc[i][f][0] + bv.x, 0.f))
                                  | ((unsigned)f2bf(fmaxf(acc[i][f][1] + bv.y, 0.f)) << 16);
                const unsigned hi = (unsigned)f2bf(fmaxf(acc[i][f][2] + bv.z, 0.f))
                                  | ((unsigned)f2bf(fmaxf(acc[i][f][3] + bv.w, 0.f)) << 16);
                *(uint2*)(Hbuf + ((size_t)(off + t0 + token) << 10) + c0) = make_uint2(lo, hi);
            }
        }
    }
}

// ---- stage2y: Y[slot][col] = bf16(H[slot] @ W2 + b2); H tile in LDS ----
// Two 32KB K-phases (32 rows x 512 cols = 2048 chunks each). SWAPPED MFMA.
__global__ __launch_bounds__(256) void stage2y_kernel(
    const unsigned short* __restrict__ Hbuf,
    const unsigned short* __restrict__ W2S, const float* __restrict__ b2,
    const int* __restrict__ counts, unsigned short* __restrict__ Ybuf)
{
    __shared__ unsigned short Hs[32 * 512];   // 32 KB
    char* HsC = (char*)Hs;

    const int bid = blockIdx.x;
    const int e  = bid & 7;
    const int nb = (bid >> 3) & 1;
    const int ti = bid >> 4;
    const int n_e = counts[e];
    const int t0 = ti << 5;
    if (t0 >= n_e) return;
    int off = 0;
#pragma unroll
    for (int i = 0; i < E_; ++i) if (i < e) off += counts[i];
    const int mact = min(32, n_e - t0);

    const int tid = threadIdx.x;
    const int wave = tid >> 6, lane = tid & 63, m = lane & 15, g = lane >> 4;
    const int colbase = nb * 256 + wave * 64;
    const int aswz = (m & 7) << 4;

    const unsigned short* Bb = W2S + ((size_t)e << 19)
                             + ((size_t)(nb * 16 + wave * 4) << 14) + (lane << 3);

    f32x4 acc[2][4];
#pragma unroll
    for (int i = 0; i < 2; ++i)
#pragma unroll
        for (int f = 0; f < 4; ++f) acc[i][f] = (f32x4){0.f, 0.f, 0.f, 0.f};

#pragma unroll
    for (int phase = 0; phase < 2; ++phase) {
        if (phase) __syncthreads();
#pragma unroll
        for (int j = 0; j < 8; ++j) {
            const int idx = tid + j * 256;   // 0..2047
            const int row = idx >> 6, c = idx & 63;
            const uint4 v = *(const uint4*)(Hbuf + ((size_t)(off + t0 + row) << 10)
                                            + phase * 512 + c * 8);
            *(uint4*)(HsC + ((row * 1024 + c * 16) ^ ((row & 7) << 4))) = v;
        }
        __syncthreads();

#pragma unroll 2
        for (int kk = 0; kk < 16; ++kk) {
            const short8v a0 = *(const short8v*)(HsC + ((m * 1024 + (kk << 6) + (g << 4)) ^ aswz));
            const short8v a1 = *(const short8v*)(HsC + (((16 + m) * 1024 + (kk << 6) + (g << 4)) ^ aswz));
            const int kg = phase * 16 + kk;
            const short8v b0  = *(const short8v*)(Bb + (kg << 9));
            const short8v b1v = *(const short8v*)(Bb + (1 << 14) + (kg << 9));
            const short8v b2v = *(const short8v*)(Bb + (2 << 14) + (kg << 9));
            const short8v b3  = *(const short8v*)(Bb + (3 << 14) + (kg << 9));
            acc[0][0] = __builtin_amdgcn_mfma_f32_16x16x32_bf16(b0,  a0, acc[0][0], 0, 0, 0);
            acc[1][0] = __builtin_amdgcn_mfma_f32_16x16x32_bf16(b0,  a1, acc[1][0], 0, 0, 0);
            acc[0][1] = __builtin_amdgcn_mfma_f32_16x16x32_bf16(b1v, a0, acc[0][1], 0, 0, 0);
            acc[1][1] = __builtin_amdgcn_mfma_f32_16x16x32_bf16(b1v, a1, acc[1][1], 0, 0, 0);
            acc[0][2] = __builtin_amdgcn_mfma_f32_16x16x32_bf16(b2v, a0, acc[0][2], 0, 0, 0);
            acc[1][2] = __builtin_amdgcn_mfma_f32_16x16x32_bf16(b2v, a1, acc[1][2], 0, 0, 0);
            acc[0][3] = __builtin_amdgcn_mfma_f32_16x16x32_bf16(b3,  a0, acc[0][3], 0, 0, 0);
            acc[1][3] = __builtin_amdgcn_mfma_f32_16x16x32_bf16(b3,  a1, acc[1][3], 0, 0, 0);
        }
    }

#pragma unroll
    for (int f = 0; f < 4; ++f) {
        const int c0 = colbase + f * 16 + 4 * g;
        const float4 bv = *(const float4*)(b2 + (e << 9) + c0);
#pragma unroll
        for (int i = 0; i < 2; ++i) {
            const int token = i * 16 + m;
            if (token < mact) {
                const unsigned lo = (unsigned)f2bf(acc[i][f][0] + bv.x)
                                  | ((unsigned)f2bf(acc[i][f][1] + bv.y) << 16);
                const unsigned hi = (unsigned)f2bf(acc[i][f][2] + bv.z)
                                  | ((unsigned)f2bf(acc[i][f][3] + bv.w) << 16);
                *(uint2*)(Ybuf + ((size_t)(off + t0 + token) << 9) + c0) = make_uint2(lo, hi);
            }
        }
    }
}

// ---- combine: out[t] = x[t] (+ g0*Y[s0] + g1*Y[s1] if masked), ALL tokens ----
__global__ __launch_bounds__(256) void combine_kernel(
    const float* __restrict__ x,
    const uchar2* __restrict__ tokE, const float2* __restrict__ tokG,
    const ushort2* __restrict__ tokSlot, const unsigned short* __restrict__ Ybuf,
    float* __restrict__ out)
{
    const int tid = threadIdx.x, wave = tid >> 6, lane = tid & 63;
    const int t = blockIdx.x * 4 + wave;
    const uchar2 ee = tokE[t];
    const float4* xrow = (const float4*)(x + ((size_t)t << 9));
    float4* orow = (float4*)(out + ((size_t)t << 9));
    if (ee.x == 255) {
        orow[lane] = xrow[lane];
        orow[lane + 64] = xrow[lane + 64];
        return;
    }
    const float2 gg = tokG[t];
    const ushort2 ss = tokSlot[t];
    const unsigned short* y0 = Ybuf + ((size_t)ss.x << 9);
    const unsigned short* y1 = Ybuf + ((size_t)ss.y << 9);
#pragma unroll
    for (int h = 0; h < 2; ++h) {
        const int idx = lane + h * 64;
        float4 o = xrow[idx];
        const uint2 a = *(const uint2*)(y0 + 4 * idx);
        const uint2 b = *(const uint2*)(y1 + 4 * idx);
        o.x += gg.x * bf2f((unsigned short)(a.x & 0xFFFF)) + gg.y * bf2f((unsigned short)(b.x & 0xFFFF));
        o.y += gg.x * bf2f((unsigned short)(a.x >> 16))    + gg.y * bf2f((unsigned short)(b.x >> 16));
        o.z += gg.x * bf2f((unsigned short)(a.y & 0xFFFF)) + gg.y * bf2f((unsigned short)(b.y & 0xFFFF));
        o.w += gg.x * bf2f((unsigned short)(a.y >> 16))    + gg.y * bf2f((unsigned short)(b.y >> 16));
        orow[idx] = o;
    }
}

// ======================= TIER B/C fallbacks =======================

__global__ __launch_bounds__(256) void gating_kernel(
    const float* __restrict__ x, const int* __restrict__ mask,
    const float* __restrict__ wg, int* __restrict__ counts,
    int* __restrict__ lists, float* __restrict__ gvals)
{
    const int wave = threadIdx.x >> 6;
    const int lane = threadIdx.x & 63;
    const int t = blockIdx.x * 4 + wave;
    const float* xr = x + (size_t)t * D_;
    float acc[E_];
#pragma unroll
    for (int e = 0; e < E_; ++e) acc[e] = 0.f;
    for (int d = lane; d < D_; d += 64) {
        const float xv = xr[d];
        const float* wr = wg + (size_t)d * E_;
#pragma unroll
        for (int e = 0; e < E_; ++e) acc[e] += xv * wr[e];
    }
#pragma unroll
    for (int e = 0; e < E_; ++e) {
        float v = acc[e];
#pragma unroll
        for (int off = 32; off > 0; off >>= 1) v += __shfl_down(v, off, 64);
        acc[e] = v;
    }
    if (lane == 0 && mask[t] != 0) {
        int i0 = 0; float v0 = acc[0];
#pragma unroll
        for (int e = 1; e < E_; ++e) if (acc[e] > v0) { v0 = acc[e]; i0 = e; }
        int i1 = -1; float v1 = -INFINITY;
#pragma unroll
        for (int e = 0; e < E_; ++e) if (e != i0 && acc[e] > v1) { v1 = acc[e]; i1 = e; }
        const float ex = __expf(v1 - v0);
        const float denom = 1.f + ex;
        const int p0 = atomicAdd(&counts[i0], 1);
        lists[i0 * NT_ + p0] = t; gvals[i0 * NT_ + p0] = 1.f / denom;
        const int p1 = atomicAdd(&counts[i1], 1);
        lists[i1 * NT_ + p1] = t; gvals[i1 * NT_ + p1] = ex / denom;
    }
}

__global__ __launch_bounds__(256) void init_out_kernel(
    const float* __restrict__ x, float* __restrict__ out)
{
    const size_t i = (size_t)blockIdx.x * blockDim.x + threadIdx.x;
    ((float4*)out)[i] = ((const float4*)x)[i];
}

__global__ __launch_bounds__(256) void transpose_cvt(
    const float* __restrict__ src, unsigned short* __restrict__ dst, int R, int C)
{
    __shared__ unsigned short t[64][72];
    const float* s = src + (size_t)blockIdx.z * R * C;
    unsigned short* d = dst + (size_t)blockIdx.z * R * C;
    const int r0 = blockIdx.y * 64, c0 = blockIdx.x * 64;
    const int tc = threadIdx.x & 63;
    const int tr = threadIdx.x >> 6;
#pragma unroll
    for (int i = 0; i < 16; ++i) {
        const int r = tr + i * 4;
        t[r][tc] = f2bf(s[(size_t)(r0 + r) * C + c0 + tc]);
    }
    __syncthreads();
    const int c = threadIdx.x >> 2;
    const int ch = threadIdx.x & 3;
#pragma unroll
    for (int half = 0; half < 2; ++half) {
        union { unsigned short u[8]; uint4 v; } p;
#pragma unroll
        for (int k = 0; k < 8; ++k) p.u[k] = t[ch * 16 + half * 8 + k][c];
        *(uint4*)(d + (size_t)(c0 + c) * R + r0 + ch * 16 + half * 8) = p.v;
    }
}

__global__ __launch_bounds__(256) void expert_mfma(
    const float* __restrict__ x,
    const unsigned short* __restrict__ W1T, const float* __restrict__ b1,
    const unsigned short* __restrict__ W2T, const float* __restrict__ b2,
    const int* __restrict__ counts, const int* __restrict__ lists,
    const float* __restrict__ gvals, float* __restrict__ out)
{
    __shared__ unsigned short Xs[TM * D_];
    __shared__ unsigned short Hs2[TM * H_];
    __shared__ int   tks[TM];
    __shared__ float gs[TM];

    const int bi = blockIdx.x;
    const int e = bi & 7;
    const int t0 = (bi >> 3) * TM;
    const int n = counts[e];
    if (t0 >= n) return;
    const int tid = threadIdx.x;
    const int mact = min(TM, n - t0);
    const int wave = tid >> 6;
    const int lane = tid & 63;
    const int m = lane & 15;
    const int g = lane >> 4;
    char* XsC = (char*)Xs;
    char* HsC = (char*)Hs2;

    if (tid < TM) {
        if (tid < mact) {
            tks[tid] = lists[e * NT_ + t0 + tid];
            gs[tid]  = gvals[e * NT_ + t0 + tid];
        } else { tks[tid] = 0; gs[tid] = 0.f; }
    }
    __syncthreads();

    for (int idx = tid; idx < TM * (D_ / 8); idx += 256) {
        const int mm = idx >> 6;
        const int c8 = idx & 63;
        union { unsigned short u[8]; uint4 v; } p;
        if (mm < mact) {
            const float4* xr = (const float4*)(x + (size_t)tks[mm] * D_);
            const float4 v0 = xr[c8 * 2], v1 = xr[c8 * 2 + 1];
            p.u[0]=f2bf(v0.x); p.u[1]=f2bf(v0.y); p.u[2]=f2bf(v0.z); p.u[3]=f2bf(v0.w);
            p.u[4]=f2bf(v1.x); p.u[5]=f2bf(v1.y); p.u[6]=f2bf(v1.z); p.u[7]=f2bf(v1.w);
        } else {
            p.v = make_uint4(0, 0, 0, 0);
        }
        const int off = mm * (D_ * 2) + c8 * 16;
        *(uint4*)(XsC + (off ^ ((mm & 7) << 4))) = p.v;
    }
    __syncthreads();

    const int nbase = wave * 256;
    f32x4 acc1[16];
#pragma unroll
    for (int f = 0; f < 16; ++f) acc1[f] = (f32x4){0.f, 0.f, 0.f, 0.f};

    for (int k0 = 0; k0 < D_; k0 += 32) {
        const int aoff = m * (D_ * 2) + k0 * 2 + g * 16;
        const short8v a = *(const short8v*)(XsC + (aoff ^ ((m & 7) << 4)));
#pragma unroll
        for (int f = 0; f < 16; ++f) {
            const unsigned short* bp = W1T + (((size_t)(e << 10) + nbase + f * 16 + m) << 9) + k0 + g * 8;
            const short8v b = *(const short8v*)bp;
            acc1[f] = __builtin_amdgcn_mfma_f32_16x16x32_bf16(a, b, acc1[f], 0, 0, 0);
        }
    }
#pragma unroll
    for (int f = 0; f < 16; ++f) {
        const int nn = nbase + f * 16 + m;
        const float bias = b1[(e << 10) + nn];
#pragma unroll
        for (int r = 0; r < 4; ++r) {
            const int mm = g * 4 + r;
            const unsigned short hv = f2bf(fmaxf(acc1[f][r] + bias, 0.f));
            const int off = mm * (H_ * 2) + nn * 2;
            *(unsigned short*)(HsC + (off ^ ((mm & 7) << 4))) = hv;
        }
    }
    __syncthreads();

    const int obase = wave * 128;
    f32x4 acc2[8];
#pragma unroll
    for (int f = 0; f < 8; ++f) acc2[f] = (f32x4){0.f, 0.f, 0.f, 0.f};

    for (int k0 = 0; k0 < H_; k0 += 32) {
        const int aoff = m * (H_ * 2) + k0 * 2 + g * 16;
        const short8v a = *(const short8v*)(HsC + (aoff ^ ((m & 7) << 4)));
#pragma unroll
        for (int f = 0; f < 8; ++f) {
            const unsigned short* bp = W2T + (((size_t)(e << 9) + obase + f * 16 + m) << 10) + k0 + g * 8;
            const short8v b = *(const short8v*)bp;
            acc2[f] = __builtin_amdgcn_mfma_f32_16x16x32_bf16(a, b, acc2[f], 0, 0, 0);
        }
    }
#pragma unroll
    for (int f = 0; f < 8; ++f) {
        const int o = obase + f * 16 + m;
        const float bias = b2[(e << 9) + o];
#pragma unroll
        for (int r = 0; r < 4; ++r) {
            const int mm = g * 4 + r;
            const float gv = gs[mm];
            if (gv != 0.f)
                atomicAdd(out + (size_t)tks[mm] * D_ + o, (acc2[f][r] + bias) * gv);
        }
    }
}

__global__ __launch_bounds__(256) void expert_fp32(
    const float* __restrict__ x,
    const float* __restrict__ W1, const float* __restrict__ b1,
    const float* __restrict__ W2, const float* __restrict__ b2,
    const int* __restrict__ counts, const int* __restrict__ lists,
    const float* __restrict__ gvals, float* __restrict__ out)
{
    __shared__ float Xs[TM][D_];
    __shared__ float Hs3[TM][H_];
    __shared__ int   tks[TM];
    __shared__ float gs[TM];

    const int e  = blockIdx.y;
    const int n  = counts[e];
    const int t0 = blockIdx.x * TM;
    if (t0 >= n) return;
    const int tid  = threadIdx.x;
    const int mact = min(TM, n - t0);

    if (tid < TM) {
        if (tid < mact) {
            tks[tid] = lists[e * NT_ + t0 + tid];
            gs[tid]  = gvals[e * NT_ + t0 + tid];
        } else { tks[tid] = 0; gs[tid] = 0.f; }
    }
    __syncthreads();
    for (int idx = tid; idx < TM * (D_ / 4); idx += 256) {
        const int mm = idx >> 7, c = idx & 127;
        float4 v = make_float4(0.f, 0.f, 0.f, 0.f);
        if (mm < mact) v = ((const float4*)(x + (size_t)tks[mm] * D_))[c];
        ((float4*)&Xs[mm][0])[c] = v;
    }
    __syncthreads();
    const float* W1e = W1 + (size_t)e * D_ * H_;
    float acc[4][TM];
#pragma unroll
    for (int jj = 0; jj < 4; ++jj)
#pragma unroll
        for (int mm = 0; mm < TM; ++mm) acc[jj][mm] = 0.f;
    for (int d4 = 0; d4 < D_ / 4; ++d4) {
        float w[4][4];
#pragma unroll
        for (int dd = 0; dd < 4; ++dd) {
            const float* wp = W1e + (size_t)(d4 * 4 + dd) * H_ + tid;
#pragma unroll
            for (int jj = 0; jj < 4; ++jj) w[dd][jj] = wp[jj * 256];
        }
#pragma unroll
        for (int mm = 0; mm < TM; ++mm) {
            const float4 xv = ((const float4*)&Xs[mm][0])[d4];
            const float* xp = &xv.x;
#pragma unroll
            for (int dd = 0; dd < 4; ++dd)
#pragma unroll
                for (int jj = 0; jj < 4; ++jj)
                    acc[jj][mm] = fmaf(xp[dd], w[dd][jj], acc[jj][mm]);
        }
    }
#pragma unroll
    for (int jj = 0; jj < 4; ++jj) {
        const int j = jj * 256 + tid;
        const float bv = b1[e * H_ + j];
#pragma unroll
        for (int mm = 0; mm < TM; ++mm) Hs3[mm][j] = fmaxf(acc[jj][mm] + bv, 0.f);
    }
    __syncthreads();
    const float* W2e = W2 + (size_t)e * H_ * D_;
    float acc2[2][TM];
#pragma unroll
    for (int oo = 0; oo < 2; ++oo)
#pragma unroll
        for (int mm = 0; mm < TM; ++mm) acc2[oo][mm] = 0.f;
    for (int j4 = 0; j4 < H_ / 4; ++j4) {
        float w[4][2];
#pragma unroll
        for (int dd = 0; dd < 4; ++dd) {
            const float* wp = W2e + (size_t)(j4 * 4 + dd) * D_ + tid;
#pragma unroll
            for (int oo = 0; oo < 2; ++oo) w[dd][oo] = wp[oo * 256];
        }
#pragma unroll
        for (int mm = 0; mm < TM; ++mm) {
            const float4 hv = ((const float4*)&Hs3[mm][0])[j4];
            const float* hp = &hv.x;
#pragma unroll
            for (int dd = 0; dd < 4; ++dd)
#pragma unroll
                for (int oo = 0; oo < 2; ++oo)
                    acc2[oo][mm] = fmaf(hp[dd], w[dd][oo], acc2[oo][mm]);
        }
    }
#pragma unroll
    for (int oo = 0; oo < 2; ++oo) {
        const int o = oo * 256 + tid;
        const float bv = b2[e * D_ + o];
        for (int mm = 0; mm < mact; ++mm)
            atomicAdd(out + (size_t)tks[mm] * D_ + o, (acc2[oo][mm] + bv) * gs[mm]);
    }
}

// ======================= host launcher =======================

extern "C" void kernel_launch(void* const* d_in, const int* in_sizes, int n_in,
                              void* d_out, int out_size, void* d_ws, size_t ws_size,
                              hipStream_t stream)
{
    const float* x    = (const float*)d_in[0];
    const int*   mask = (const int*)d_in[1];
    const float* wg   = (const float*)d_in[2];
    const float* W1   = (const float*)d_in[3];
    const float* b1   = (const float*)d_in[4];
    const float* W2   = (const float*)d_in[5];
    const float* b2   = (const float*)d_in[6];
    float* out = (float*)d_out;

    char* ws = (char*)d_ws;
    int*   counts = (int*)ws;                       // 32 B
    int*   lists  = (int*)(ws + 256);               // 128 KB
    float* gvals  = (float*)(ws + 256 + 131072);    // 128 KB

    // Tier A layout
    ushort2* tokSlot = (ushort2*)(ws + 0x42000);                        // 16 KB
    uchar2* tokE = (uchar2*)(ws + 0x48000);                             // 8 KB
    float2* tokG = (float2*)(ws + 0x50000);                             // 32 KB
    ushort2* locs = (ushort2*)(ws + 0x58000);                           // 16 KB
    int* blockCnt = (int*)(ws + 0x5C000);                               // 512 B
    unsigned short* xbf  = (unsigned short*)(ws + 0x60000);             // 4 MB
    unsigned short* W1Sa = (unsigned short*)(ws + 0x480000);            // 8 MB
    unsigned short* W2Sa = (unsigned short*)(ws + 0xC80000);            // 8 MB
    unsigned short* Hbuf = (unsigned short*)(ws + 0x1480000);           // 16.5 MB
    unsigned short* Ybuf = (unsigned short*)(ws + 0x2500000);           // 8.25 MB
    const size_t needA2 = 0x2500000 + (size_t)8448 * 512 * 2;           // ~47.1 MB

    const size_t wt_bytes = (size_t)E_ * D_ * H_ * 2;
    const size_t needB = 524288 + 2 * wt_bytes;                         // ~17.3 MB

    if (ws_size >= needA2) {
        prep_fused<<<2048, 256, 0, stream>>>(x, mask, wg, W1, W2,
                                             xbf, tokE, tokG, W1Sa, W2Sa);
        build1_kernel<<<16, 256, 0, stream>>>(tokE, locs, blockCnt);
        build2_kernel<<<16, 256, 0, stream>>>(tokE, tokG, locs, blockCnt,
                                              counts, lists, gvals, tokSlot);
        stage1_kernel<<<MAXTILE * 2 * 8, 256, 0, stream>>>(xbf, W1Sa, b1, counts, lists, Hbuf);
        stage2y_kernel<<<MAXTILE * 2 * 8, 256, 0, stream>>>(Hbuf, W2Sa, b2, counts, Ybuf);
        combine_kernel<<<1024, 256, 0, stream>>>(x, tokE, tokG, tokSlot, Ybuf, out);
    } else if (ws_size >= needB) {
        unsigned short* W1T = (unsigned short*)(ws + 524288);
        unsigned short* W2T = (unsigned short*)(ws + 524288 + wt_bytes);
        hipMemsetAsync(counts, 0, E_ * sizeof(int), stream);
        gating_kernel<<<NT_ / 4, 256, 0, stream>>>(x, mask, wg, counts, lists, gvals);
        init_out_kernel<<<(NT_ * D_) / 4 / 256, 256, 0, stream>>>(x, out);
        transpose_cvt<<<dim3(H_ / 64, D_ / 64, E_), 256, 0, stream>>>(W1, W1T, D_, H_);
        transpose_cvt<<<dim3(D_ / 64, H_ / 64, E_), 256, 0, stream>>>(W2, W2T, H_, D_);
        expert_mfma<<<(NT_ / TM) * E_, 256, 0, stream>>>(x, W1T, b1, W2T, b2,
                                                         counts, lists, gvals, out);
    } else {
        hipMemsetAsync(counts, 0, E_ * sizeof(int), stream);
        gating_kernel<<<NT_ / 4, 256, 0, stream>>>(x, mask, wg, counts, lists, gvals);
        init_out_kernel<<<(NT_ * D_) / 4 / 256, 256, 0, stream>>>(x, out);
        expert_fp32<<<dim3(NT_ / TM, E_), 256, 0, stream>>>(x, W1, b1, W2, b2,
                                                            counts, lists, gvals, out);
    }
}

// Round 22
// 61.082 us; speedup vs baseline: 1.1723x; 1.1723x over previous
//
#include <hip/hip_runtime.h>
#include <cmath>

#define B_ 8
#define S_ 512
#define D_ 512
#define H_ 1024
#define E_ 8
#define NT_ (B_*S_)   // 4096 tokens
#define TM 16         // tokens per tile (fallback path)
#define MAXTILE 40    // tiles per expert (capacity 1280 tokens/expert)

typedef __attribute__((ext_vector_type(8))) short short8v;
typedef __attribute__((ext_vector_type(4))) float f32x4;

__device__ inline unsigned short f2bf(float f) {
    union { float f; unsigned u; } a; a.f = f;
    unsigned u = a.u;
    return (unsigned short)((u + 0x7FFF + ((u >> 16) & 1)) >> 16);  // RNE
}
__device__ inline float bf2f(unsigned short u) {
    union { unsigned u; float f; } a; a.u = ((unsigned)u) << 16; return a.f;
}

// ======================= TIER A (main path) =======================

// ---- prep_fused ----
// blocks 0..1023   : xbf = bf16(x), per-token gating (no atomics; out NOT written)
// blocks 1024..1535: W1 repack; 1536..2047: W2 repack (4 chunks/wave).
__global__ __launch_bounds__(256) void prep_fused(
    const float* __restrict__ x, const int* __restrict__ mask,
    const float* __restrict__ wg,
    const float* __restrict__ W1, const float* __restrict__ W2,
    unsigned short* __restrict__ xbf,
    uchar2* __restrict__ tokE, float2* __restrict__ tokG,
    unsigned short* __restrict__ W1S, unsigned short* __restrict__ W2S)
{
    const int tid = threadIdx.x, wave = tid >> 6, lane = tid & 63;
    const int bid = blockIdx.x;

    if (bid < 1024) {
        const int t = bid * 4 + wave;
        const float4* xr = (const float4*)(x + ((size_t)t << 9));
        const float4 v0 = xr[lane];
        const float4 v1 = xr[lane + 64];
        union { unsigned short u[4]; uint2 w; } pa, pb;
        pa.u[0]=f2bf(v0.x); pa.u[1]=f2bf(v0.y); pa.u[2]=f2bf(v0.z); pa.u[3]=f2bf(v0.w);
        pb.u[0]=f2bf(v1.x); pb.u[1]=f2bf(v1.y); pb.u[2]=f2bf(v1.z); pb.u[3]=f2bf(v1.w);
        uint2* xrow = (uint2*)(xbf + ((size_t)t << 9));
        xrow[lane] = pa.w; xrow[lane + 64] = pb.w;

        float acc[E_];
#pragma unroll
        for (int e = 0; e < E_; ++e) acc[e] = 0.f;
        const int d0 = lane * 4;
#pragma unroll
        for (int dd = 0; dd < 4; ++dd) {
            const float xa = (&v0.x)[dd], xb = (&v1.x)[dd];
            const float4 wa0 = *(const float4*)(wg + (size_t)(d0 + dd) * 8);
            const float4 wa1 = *(const float4*)(wg + (size_t)(d0 + dd) * 8 + 4);
            const float4 wb0 = *(const float4*)(wg + (size_t)(256 + d0 + dd) * 8);
            const float4 wb1 = *(const float4*)(wg + (size_t)(256 + d0 + dd) * 8 + 4);
            acc[0] += xa * wa0.x + xb * wb0.x;
            acc[1] += xa * wa0.y + xb * wb0.y;
            acc[2] += xa * wa0.z + xb * wb0.z;
            acc[3] += xa * wa0.w + xb * wb0.w;
            acc[4] += xa * wa1.x + xb * wb1.x;
            acc[5] += xa * wa1.y + xb * wb1.y;
            acc[6] += xa * wa1.z + xb * wb1.z;
            acc[7] += xa * wa1.w + xb * wb1.w;
        }
#pragma unroll
        for (int e = 0; e < E_; ++e) {
            float v = acc[e];
#pragma unroll
            for (int off = 32; off > 0; off >>= 1) v += __shfl_xor(v, off, 64);
            acc[e] = v;
        }
        if (lane == 0) {
            if (mask[t] != 0) {
                int i0 = 0; float v0m = acc[0];
#pragma unroll
                for (int e = 1; e < E_; ++e) if (acc[e] > v0m) { v0m = acc[e]; i0 = e; }
                int i1 = -1; float v1m = -INFINITY;
#pragma unroll
                for (int e = 0; e < E_; ++e) if (e != i0 && acc[e] > v1m) { v1m = acc[e]; i1 = e; }
                const float ex = __expf(v1m - v0m);
                const float denom = 1.f + ex;
                tokE[t] = make_uchar2((unsigned char)i0, (unsigned char)i1);
                tokG[t] = make_float2(1.f / denom, ex / denom);
            } else {
                tokE[t] = make_uchar2(255, 255);
            }
        }
        return;
    }

    // -------- direct repack: one wave -> four 1KB chunks (64 cols) --------
    const int isW2 = (bid >= 1536);
    const int q = ((bid - (isW2 ? 1536 : 1024)) << 2) | wave;   // 0..2047
    const int e = q >> 8, rem = q & 255;
    const int g = lane >> 4, m = lane & 15;
    const float* base; unsigned short* dstB; int stride, K32, Fq, kidx;
    if (!isW2) {
        Fq = rem >> 4; kidx = rem & 15;
        stride = H_; K32 = 16; base = W1; dstB = W1S;
    } else {
        Fq = rem >> 5; kidx = rem & 31;
        stride = D_; K32 = 32; base = W2; dstB = W2S;
    }
    const int k = kidx * 32 + g * 8;
    const float* src = base + ((size_t)e << 19) + (size_t)k * stride + Fq * 64 + m;
    float v[4][8];
#pragma unroll
    for (int j = 0; j < 8; ++j) {
#pragma unroll
        for (int c = 0; c < 4; ++c)
            v[c][j] = src[(size_t)j * stride + c * 16];
    }
#pragma unroll
    for (int c = 0; c < 4; ++c) {
        union { unsigned short u[8]; uint4 qv; } p;
#pragma unroll
        for (int j = 0; j < 8; ++j) p.u[j] = f2bf(v[c][j]);
        unsigned short* dst = dstB + ((size_t)e << 19)
                            + ((size_t)((Fq * 4 + c) * K32 + kidx) << 9) + lane * 8;
        *(uint4*)dst = p.qv;
    }
}

// ---- build1: 16 blocks x 256 thr, one token each ----
__global__ __launch_bounds__(256) void build1_kernel(
    const uchar2* __restrict__ tokE,
    ushort2* __restrict__ locs, int* __restrict__ blockCnt)
{
    __shared__ int waveTot[4][E_];
    const int tid = threadIdx.x, lane = tid & 63, wave = tid >> 6;
    const int t = blockIdx.x * 256 + tid;
    const uchar2 ee = tokE[t];
    int scan_pre[E_];
#pragma unroll
    for (int e = 0; e < E_; ++e) {
        const int orig = (ee.x == e) + (ee.y == e);
        int v = orig;
#pragma unroll
        for (int off = 1; off < 64; off <<= 1) {
            const int o = __shfl_up(v, off, 64);
            if (lane >= off) v += o;
        }
        scan_pre[e] = v - orig;
        if (lane == 63) waveTot[wave][e] = v;
    }
    __syncthreads();
    int loc0 = 0, loc1 = 0;
#pragma unroll
    for (int e = 0; e < E_; ++e) {
        int add = 0;
#pragma unroll
        for (int w = 0; w < 4; ++w) if (w < wave) add += waveTot[w][e];
        const int pre = scan_pre[e] + add;
        if (ee.x == e) loc0 = pre;
        if (ee.y == e) loc1 = pre;
    }
    if (tid < E_)
        blockCnt[blockIdx.x * E_ + tid] =
            waveTot[0][tid] + waveTot[1][tid] + waveTot[2][tid] + waveTot[3][tid];
    if (ee.x != 255)
        locs[t] = make_ushort2((unsigned short)loc0, (unsigned short)loc1);
}

// ---- build2: scatter lists (within-expert) + tokSlot (GLOBAL slot) ----
__global__ __launch_bounds__(256) void build2_kernel(
    const uchar2* __restrict__ tokE, const float2* __restrict__ tokG,
    const ushort2* __restrict__ locs, const int* __restrict__ blockCnt,
    int* __restrict__ counts, int* __restrict__ lists, float* __restrict__ gvals,
    ushort2* __restrict__ tokSlot)
{
    __shared__ int bc[16][E_];
    const int tid = threadIdx.x;
    const int b = blockIdx.x;
    if (tid < 16 * E_) bc[tid >> 3][tid & 7] = blockCnt[tid];
    __syncthreads();
    if (b == 0 && tid < E_) {
        int s = 0;
#pragma unroll
        for (int bb = 0; bb < 16; ++bb) s += bc[bb][tid];
        counts[tid] = s;
    }
    const int t = b * 256 + tid;
    const uchar2 ee = tokE[t];
    if (ee.x == 255) return;
    int base0 = 0, base1 = 0, ex0 = 0, ex1 = 0, cum = 0;
#pragma unroll
    for (int e = 0; e < E_; ++e) {
        int boff = 0, tot = 0;
#pragma unroll
        for (int bb = 0; bb < 16; ++bb) {
            const int v = bc[bb][e];
            tot += v;
            if (bb < b) boff += v;
        }
        if (ee.x == e) { base0 = boff; ex0 = cum; }
        if (ee.y == e) { base1 = boff; ex1 = cum; }
        cum += tot;
    }
    const ushort2 lc = locs[t];
    const float2 gg = tokG[t];
    const int s0 = ee.x * NT_ + base0 + lc.x;
    const int s1 = ee.y * NT_ + base1 + lc.y;
    lists[s0] = t; gvals[s0] = gg.x;
    lists[s1] = t; gvals[s1] = gg.y;
    tokSlot[t] = make_ushort2((unsigned short)(ex0 + base0 + lc.x),
                              (unsigned short)(ex1 + base1 + lc.y));
}

// ---- stage1: H[slot][h] = relu(Xbf[tok] @ W1 + b1); X tile in LDS ----
// SWAPPED MFMA; 4-way col-split (R20 best): lane (g,m) holds 4 consecutive
// h-cols (4g+r) of token m -> 8B uint2 Hbuf stores.
__global__ __launch_bounds__(256) void stage1_kernel(
    const unsigned short* __restrict__ xbf,
    const unsigned short* __restrict__ W1S, const float* __restrict__ b1,
    const int* __restrict__ counts, const int* __restrict__ lists,
    unsigned short* __restrict__ Hbuf)
{
    __shared__ int tks[32];
    __shared__ unsigned short Xs[32 * D_];   // 32 KB
    char* XsC = (char*)Xs;

    const int bid = blockIdx.x;
    const int e  = bid & 7;
    const int nb = (bid >> 3) & 3;
    const int ti = bid >> 5;
    const int n_e = counts[e];
    const int t0 = ti << 5;
    if (t0 >= n_e) return;
    int off = 0;
#pragma unroll
    for (int i = 0; i < E_; ++i) if (i < e) off += counts[i];
    const int mact = min(32, n_e - t0);
    const int tid = threadIdx.x;
    if (tid < 32) tks[tid] = lists[e * NT_ + t0 + min(tid, mact - 1)];
    __syncthreads();

    // stage X tile: 2048 16B chunks, 8 per thread; row reads fully coalesced
#pragma unroll
    for (int j = 0; j < 8; ++j) {
        const int idx = tid + j * 256;       // 0..2047
        const int row = idx >> 6, c = idx & 63;
        const uint4 v = *(const uint4*)(xbf + ((size_t)tks[row] << 9) + c * 8);
        *(uint4*)(XsC + ((row * 1024 + c * 16) ^ ((row & 7) << 4))) = v;
    }
    __syncthreads();

    const int wave = tid >> 6, lane = tid & 63, m = lane & 15, g = lane >> 4;
    const int colbase = nb * 256 + wave * 64;

    const int aoff0 = m * 1024 + (g << 4);
    const int aoff1 = (16 + m) * 1024 + (g << 4);
    const int aswz  = (m & 7) << 4;
    const unsigned short* Bb = W1S + ((size_t)e << 19)
                             + ((size_t)(nb * 16 + wave * 4) << 13) + (lane << 3);

    f32x4 acc[2][4];
#pragma unroll
    for (int i = 0; i < 2; ++i)
#pragma unroll
        for (int f = 0; f < 4; ++f) acc[i][f] = (f32x4){0.f, 0.f, 0.f, 0.f};

#pragma unroll 2
    for (int kk = 0; kk < 16; ++kk) {
        const short8v a0 = *(const short8v*)(XsC + ((aoff0 + (kk << 6)) ^ aswz));
        const short8v a1 = *(const short8v*)(XsC + ((aoff1 + (kk << 6)) ^ aswz));
        const short8v b0  = *(const short8v*)(Bb + (kk << 9));
        const short8v b1v = *(const short8v*)(Bb + (1 << 13) + (kk << 9));
        const short8v b2v = *(const short8v*)(Bb + (2 << 13) + (kk << 9));
        const short8v b3  = *(const short8v*)(Bb + (3 << 13) + (kk << 9));
        acc[0][0] = __builtin_amdgcn_mfma_f32_16x16x32_bf16(b0,  a0, acc[0][0], 0, 0, 0);
        acc[1][0] = __builtin_amdgcn_mfma_f32_16x16x32_bf16(b0,  a1, acc[1][0], 0, 0, 0);
        acc[0][1] = __builtin_amdgcn_mfma_f32_16x16x32_bf16(b1v, a0, acc[0][1], 0, 0, 0);
        acc[1][1] = __builtin_amdgcn_mfma_f32_16x16x32_bf16(b1v, a1, acc[1][1], 0, 0, 0);
        acc[0][2] = __builtin_amdgcn_mfma_f32_16x16x32_bf16(b2v, a0, acc[0][2], 0, 0, 0);
        acc[1][2] = __builtin_amdgcn_mfma_f32_16x16x32_bf16(b2v, a1, acc[1][2], 0, 0, 0);
        acc[0][3] = __builtin_amdgcn_mfma_f32_16x16x32_bf16(b3,  a0, acc[0][3], 0, 0, 0);
        acc[1][3] = __builtin_amdgcn_mfma_f32_16x16x32_bf16(b3,  a1, acc[1][3], 0, 0, 0);
    }

    // epilogue: lane (g,m) holds h-cols c0..c0+3 of token i*16+m; 8B stores
#pragma unroll
    for (int f = 0; f < 4; ++f) {
        const int c0 = colbase + f * 16 + 4 * g;
        const float4 bv = *(const float4*)(b1 + (e << 10) + c0);
#pragma unroll
        for (int i = 0; i < 2; ++i) {
            const int token = i * 16 + m;
            if (token < mact) {
                const unsigned lo = (unsigned)f2bf(fmaxf(acc[i][f][0] + bv.x, 0.f))
                                  | ((unsigned)f2bf(fmaxf(acc[i][f][1] + bv.y, 0.f)) << 16);
                const unsigned hi = (unsigned)f2bf(fmaxf(acc[i][f][2] + bv.z, 0.f))
                                  | ((unsigned)f2bf(fmaxf(acc[i][f][3] + bv.w, 0.f)) << 16);
                *(uint2*)(Hbuf + ((size_t)(off + t0 + token) << 10) + c0) = make_uint2(lo, hi);
            }
        }
    }
}

// ---- stage2y: Y[slot][col] = bf16(H[slot] @ W2 + b2); H tile in LDS ----
// Two 32KB K-phases (32 rows x 512 cols = 2048 chunks each). SWAPPED MFMA.
__global__ __launch_bounds__(256) void stage2y_kernel(
    const unsigned short* __restrict__ Hbuf,
    const unsigned short* __restrict__ W2S, const float* __restrict__ b2,
    const int* __restrict__ counts, unsigned short* __restrict__ Ybuf)
{
    __shared__ unsigned short Hs[32 * 512];   // 32 KB
    char* HsC = (char*)Hs;

    const int bid = blockIdx.x;
    const int e  = bid & 7;
    const int nb = (bid >> 3) & 1;
    const int ti = bid >> 4;
    const int n_e = counts[e];
    const int t0 = ti << 5;
    if (t0 >= n_e) return;
    int off = 0;
#pragma unroll
    for (int i = 0; i < E_; ++i) if (i < e) off += counts[i];
    const int mact = min(32, n_e - t0);

    const int tid = threadIdx.x;
    const int wave = tid >> 6, lane = tid & 63, m = lane & 15, g = lane >> 4;
    const int colbase = nb * 256 + wave * 64;
    const int aswz = (m & 7) << 4;

    const unsigned short* Bb = W2S + ((size_t)e << 19)
                             + ((size_t)(nb * 16 + wave * 4) << 14) + (lane << 3);

    f32x4 acc[2][4];
#pragma unroll
    for (int i = 0; i < 2; ++i)
#pragma unroll
        for (int f = 0; f < 4; ++f) acc[i][f] = (f32x4){0.f, 0.f, 0.f, 0.f};

#pragma unroll
    for (int phase = 0; phase < 2; ++phase) {
        if (phase) __syncthreads();
#pragma unroll
        for (int j = 0; j < 8; ++j) {
            const int idx = tid + j * 256;   // 0..2047
            const int row = idx >> 6, c = idx & 63;
            const uint4 v = *(const uint4*)(Hbuf + ((size_t)(off + t0 + row) << 10)
                                            + phase * 512 + c * 8);
            *(uint4*)(HsC + ((row * 1024 + c * 16) ^ ((row & 7) << 4))) = v;
        }
        __syncthreads();

#pragma unroll 2
        for (int kk = 0; kk < 16; ++kk) {
            const short8v a0 = *(const short8v*)(HsC + ((m * 1024 + (kk << 6) + (g << 4)) ^ aswz));
            const short8v a1 = *(const short8v*)(HsC + (((16 + m) * 1024 + (kk << 6) + (g << 4)) ^ aswz));
            const int kg = phase * 16 + kk;
            const short8v b0  = *(const short8v*)(Bb + (kg << 9));
            const short8v b1v = *(const short8v*)(Bb + (1 << 14) + (kg << 9));
            const short8v b2v = *(const short8v*)(Bb + (2 << 14) + (kg << 9));
            const short8v b3  = *(const short8v*)(Bb + (3 << 14) + (kg << 9));
            acc[0][0] = __builtin_amdgcn_mfma_f32_16x16x32_bf16(b0,  a0, acc[0][0], 0, 0, 0);
            acc[1][0] = __builtin_amdgcn_mfma_f32_16x16x32_bf16(b0,  a1, acc[1][0], 0, 0, 0);
            acc[0][1] = __builtin_amdgcn_mfma_f32_16x16x32_bf16(b1v, a0, acc[0][1], 0, 0, 0);
            acc[1][1] = __builtin_amdgcn_mfma_f32_16x16x32_bf16(b1v, a1, acc[1][1], 0, 0, 0);
            acc[0][2] = __builtin_amdgcn_mfma_f32_16x16x32_bf16(b2v, a0, acc[0][2], 0, 0, 0);
            acc[1][2] = __builtin_amdgcn_mfma_f32_16x16x32_bf16(b2v, a1, acc[1][2], 0, 0, 0);
            acc[0][3] = __builtin_amdgcn_mfma_f32_16x16x32_bf16(b3,  a0, acc[0][3], 0, 0, 0);
            acc[1][3] = __builtin_amdgcn_mfma_f32_16x16x32_bf16(b3,  a1, acc[1][3], 0, 0, 0);
        }
    }

#pragma unroll
    for (int f = 0; f < 4; ++f) {
        const int c0 = colbase + f * 16 + 4 * g;
        const float4 bv = *(const float4*)(b2 + (e << 9) + c0);
#pragma unroll
        for (int i = 0; i < 2; ++i) {
            const int token = i * 16 + m;
            if (token < mact) {
                const unsigned lo = (unsigned)f2bf(acc[i][f][0] + bv.x)
                                  | ((unsigned)f2bf(acc[i][f][1] + bv.y) << 16);
                const unsigned hi = (unsigned)f2bf(acc[i][f][2] + bv.z)
                                  | ((unsigned)f2bf(acc[i][f][3] + bv.w) << 16);
                *(uint2*)(Ybuf + ((size_t)(off + t0 + token) << 9) + c0) = make_uint2(lo, hi);
            }
        }
    }
}

// ---- combine: out[t] = x[t] (+ g0*Y[s0] + g1*Y[s1] if masked), ALL tokens ----
__global__ __launch_bounds__(256) void combine_kernel(
    const float* __restrict__ x,
    const uchar2* __restrict__ tokE, const float2* __restrict__ tokG,
    const ushort2* __restrict__ tokSlot, const unsigned short* __restrict__ Ybuf,
    float* __restrict__ out)
{
    const int tid = threadIdx.x, wave = tid >> 6, lane = tid & 63;
    const int t = blockIdx.x * 4 + wave;
    const uchar2 ee = tokE[t];
    const float4* xrow = (const float4*)(x + ((size_t)t << 9));
    float4* orow = (float4*)(out + ((size_t)t << 9));
    if (ee.x == 255) {
        orow[lane] = xrow[lane];
        orow[lane + 64] = xrow[lane + 64];
        return;
    }
    const float2 gg = tokG[t];
    const ushort2 ss = tokSlot[t];
    const unsigned short* y0 = Ybuf + ((size_t)ss.x << 9);
    const unsigned short* y1 = Ybuf + ((size_t)ss.y << 9);
#pragma unroll
    for (int h = 0; h < 2; ++h) {
        const int idx = lane + h * 64;
        float4 o = xrow[idx];
        const uint2 a = *(const uint2*)(y0 + 4 * idx);
        const uint2 b = *(const uint2*)(y1 + 4 * idx);
        o.x += gg.x * bf2f((unsigned short)(a.x & 0xFFFF)) + gg.y * bf2f((unsigned short)(b.x & 0xFFFF));
        o.y += gg.x * bf2f((unsigned short)(a.x >> 16))    + gg.y * bf2f((unsigned short)(b.x >> 16));
        o.z += gg.x * bf2f((unsigned short)(a.y & 0xFFFF)) + gg.y * bf2f((unsigned short)(b.y & 0xFFFF));
        o.w += gg.x * bf2f((unsigned short)(a.y >> 16))    + gg.y * bf2f((unsigned short)(b.y >> 16));
        orow[idx] = o;
    }
}

// ======================= TIER B/C fallbacks =======================

__global__ __launch_bounds__(256) void gating_kernel(
    const float* __restrict__ x, const int* __restrict__ mask,
    const float* __restrict__ wg, int* __restrict__ counts,
    int* __restrict__ lists, float* __restrict__ gvals)
{
    const int wave = threadIdx.x >> 6;
    const int lane = threadIdx.x & 63;
    const int t = blockIdx.x * 4 + wave;
    const float* xr = x + (size_t)t * D_;
    float acc[E_];
#pragma unroll
    for (int e = 0; e < E_; ++e) acc[e] = 0.f;
    for (int d = lane; d < D_; d += 64) {
        const float xv = xr[d];
        const float* wr = wg + (size_t)d * E_;
#pragma unroll
        for (int e = 0; e < E_; ++e) acc[e] += xv * wr[e];
    }
#pragma unroll
    for (int e = 0; e < E_; ++e) {
        float v = acc[e];
#pragma unroll
        for (int off = 32; off > 0; off >>= 1) v += __shfl_down(v, off, 64);
        acc[e] = v;
    }
    if (lane == 0 && mask[t] != 0) {
        int i0 = 0; float v0 = acc[0];
#pragma unroll
        for (int e = 1; e < E_; ++e) if (acc[e] > v0) { v0 = acc[e]; i0 = e; }
        int i1 = -1; float v1 = -INFINITY;
#pragma unroll
        for (int e = 0; e < E_; ++e) if (e != i0 && acc[e] > v1) { v1 = acc[e]; i1 = e; }
        const float ex = __expf(v1 - v0);
        const float denom = 1.f + ex;
        const int p0 = atomicAdd(&counts[i0], 1);
        lists[i0 * NT_ + p0] = t; gvals[i0 * NT_ + p0] = 1.f / denom;
        const int p1 = atomicAdd(&counts[i1], 1);
        lists[i1 * NT_ + p1] = t; gvals[i1 * NT_ + p1] = ex / denom;
    }
}

__global__ __launch_bounds__(256) void init_out_kernel(
    const float* __restrict__ x, float* __restrict__ out)
{
    const size_t i = (size_t)blockIdx.x * blockDim.x + threadIdx.x;
    ((float4*)out)[i] = ((const float4*)x)[i];
}

__global__ __launch_bounds__(256) void transpose_cvt(
    const float* __restrict__ src, unsigned short* __restrict__ dst, int R, int C)
{
    __shared__ unsigned short t[64][72];
    const float* s = src + (size_t)blockIdx.z * R * C;
    unsigned short* d = dst + (size_t)blockIdx.z * R * C;
    const int r0 = blockIdx.y * 64, c0 = blockIdx.x * 64;
    const int tc = threadIdx.x & 63;
    const int tr = threadIdx.x >> 6;
#pragma unroll
    for (int i = 0; i < 16; ++i) {
        const int r = tr + i * 4;
        t[r][tc] = f2bf(s[(size_t)(r0 + r) * C + c0 + tc]);
    }
    __syncthreads();
    const int c = threadIdx.x >> 2;
    const int ch = threadIdx.x & 3;
#pragma unroll
    for (int half = 0; half < 2; ++half) {
        union { unsigned short u[8]; uint4 v; } p;
#pragma unroll
        for (int k = 0; k < 8; ++k) p.u[k] = t[ch * 16 + half * 8 + k][c];
        *(uint4*)(d + (size_t)(c0 + c) * R + r0 + ch * 16 + half * 8) = p.v;
    }
}

__global__ __launch_bounds__(256) void expert_mfma(
    const float* __restrict__ x,
    const unsigned short* __restrict__ W1T, const float* __restrict__ b1,
    const unsigned short* __restrict__ W2T, const float* __restrict__ b2,
    const int* __restrict__ counts, const int* __restrict__ lists,
    const float* __restrict__ gvals, float* __restrict__ out)
{
    __shared__ unsigned short Xs[TM * D_];
    __shared__ unsigned short Hs2[TM * H_];
    __shared__ int   tks[TM];
    __shared__ float gs[TM];

    const int bi = blockIdx.x;
    const int e = bi & 7;
    const int t0 = (bi >> 3) * TM;
    const int n = counts[e];
    if (t0 >= n) return;
    const int tid = threadIdx.x;
    const int mact = min(TM, n - t0);
    const int wave = tid >> 6;
    const int lane = tid & 63;
    const int m = lane & 15;
    const int g = lane >> 4;
    char* XsC = (char*)Xs;
    char* HsC = (char*)Hs2;

    if (tid < TM) {
        if (tid < mact) {
            tks[tid] = lists[e * NT_ + t0 + tid];
            gs[tid]  = gvals[e * NT_ + t0 + tid];
        } else { tks[tid] = 0; gs[tid] = 0.f; }
    }
    __syncthreads();

    for (int idx = tid; idx < TM * (D_ / 8); idx += 256) {
        const int mm = idx >> 6;
        const int c8 = idx & 63;
        union { unsigned short u[8]; uint4 v; } p;
        if (mm < mact) {
            const float4* xr = (const float4*)(x + (size_t)tks[mm] * D_);
            const float4 v0 = xr[c8 * 2], v1 = xr[c8 * 2 + 1];
            p.u[0]=f2bf(v0.x); p.u[1]=f2bf(v0.y); p.u[2]=f2bf(v0.z); p.u[3]=f2bf(v0.w);
            p.u[4]=f2bf(v1.x); p.u[5]=f2bf(v1.y); p.u[6]=f2bf(v1.z); p.u[7]=f2bf(v1.w);
        } else {
            p.v = make_uint4(0, 0, 0, 0);
        }
        const int off = mm * (D_ * 2) + c8 * 16;
        *(uint4*)(XsC + (off ^ ((mm & 7) << 4))) = p.v;
    }
    __syncthreads();

    const int nbase = wave * 256;
    f32x4 acc1[16];
#pragma unroll
    for (int f = 0; f < 16; ++f) acc1[f] = (f32x4){0.f, 0.f, 0.f, 0.f};

    for (int k0 = 0; k0 < D_; k0 += 32) {
        const int aoff = m * (D_ * 2) + k0 * 2 + g * 16;
        const short8v a = *(const short8v*)(XsC + (aoff ^ ((m & 7) << 4)));
#pragma unroll
        for (int f = 0; f < 16; ++f) {
            const unsigned short* bp = W1T + (((size_t)(e << 10) + nbase + f * 16 + m) << 9) + k0 + g * 8;
            const short8v b = *(const short8v*)bp;
            acc1[f] = __builtin_amdgcn_mfma_f32_16x16x32_bf16(a, b, acc1[f], 0, 0, 0);
        }
    }
#pragma unroll
    for (int f = 0; f < 16; ++f) {
        const int nn = nbase + f * 16 + m;
        const float bias = b1[(e << 10) + nn];
#pragma unroll
        for (int r = 0; r < 4; ++r) {
            const int mm = g * 4 + r;
            const unsigned short hv = f2bf(fmaxf(acc1[f][r] + bias, 0.f));
            const int off = mm * (H_ * 2) + nn * 2;
            *(unsigned short*)(HsC + (off ^ ((mm & 7) << 4))) = hv;
        }
    }
    __syncthreads();

    const int obase = wave * 128;
    f32x4 acc2[8];
#pragma unroll
    for (int f = 0; f < 8; ++f) acc2[f] = (f32x4){0.f, 0.f, 0.f, 0.f};

    for (int k0 = 0; k0 < H_; k0 += 32) {
        const int aoff = m * (H_ * 2) + k0 * 2 + g * 16;
        const short8v a = *(const short8v*)(HsC + (aoff ^ ((m & 7) << 4)));
#pragma unroll
        for (int f = 0; f < 8; ++f) {
            const unsigned short* bp = W2T + (((size_t)(e << 9) + obase + f * 16 + m) << 10) + k0 + g * 8;
            const short8v b = *(const short8v*)bp;
            acc2[f] = __builtin_amdgcn_mfma_f32_16x16x32_bf16(a, b, acc2[f], 0, 0, 0);
        }
    }
#pragma unroll
    for (int f = 0; f < 8; ++f) {
        const int o = obase + f * 16 + m;
        const float bias = b2[(e << 9) + o];
#pragma unroll
        for (int r = 0; r < 4; ++r) {
            const int mm = g * 4 + r;
            const float gv = gs[mm];
            if (gv != 0.f)
                atomicAdd(out + (size_t)tks[mm] * D_ + o, (acc2[f][r] + bias) * gv);
        }
    }
}

__global__ __launch_bounds__(256) void expert_fp32(
    const float* __restrict__ x,
    const float* __restrict__ W1, const float* __restrict__ b1,
    const float* __restrict__ W2, const float* __restrict__ b2,
    const int* __restrict__ counts, const int* __restrict__ lists,
    const float* __restrict__ gvals, float* __restrict__ out)
{
    __shared__ float Xs[TM][D_];
    __shared__ float Hs3[TM][H_];
    __shared__ int   tks[TM];
    __shared__ float gs[TM];

    const int e  = blockIdx.y;
    const int n  = counts[e];
    const int t0 = blockIdx.x * TM;
    if (t0 >= n) return;
    const int tid  = threadIdx.x;
    const int mact = min(TM, n - t0);

    if (tid < TM) {
        if (tid < mact) {
            tks[tid] = lists[e * NT_ + t0 + tid];
            gs[tid]  = gvals[e * NT_ + t0 + tid];
        } else { tks[tid] = 0; gs[tid] = 0.f; }
    }
    __syncthreads();
    for (int idx = tid; idx < TM * (D_ / 4); idx += 256) {
        const int mm = idx >> 7, c = idx & 127;
        float4 v = make_float4(0.f, 0.f, 0.f, 0.f);
        if (mm < mact) v = ((const float4*)(x + (size_t)tks[mm] * D_))[c];
        ((float4*)&Xs[mm][0])[c] = v;
    }
    __syncthreads();
    const float* W1e = W1 + (size_t)e * D_ * H_;
    float acc[4][TM];
#pragma unroll
    for (int jj = 0; jj < 4; ++jj)
#pragma unroll
        for (int mm = 0; mm < TM; ++mm) acc[jj][mm] = 0.f;
    for (int d4 = 0; d4 < D_ / 4; ++d4) {
        float w[4][4];
#pragma unroll
        for (int dd = 0; dd < 4; ++dd) {
            const float* wp = W1e + (size_t)(d4 * 4 + dd) * H_ + tid;
#pragma unroll
            for (int jj = 0; jj < 4; ++jj) w[dd][jj] = wp[jj * 256];
        }
#pragma unroll
        for (int mm = 0; mm < TM; ++mm) {
            const float4 xv = ((const float4*)&Xs[mm][0])[d4];
            const float* xp = &xv.x;
#pragma unroll
            for (int dd = 0; dd < 4; ++dd)
#pragma unroll
                for (int jj = 0; jj < 4; ++jj)
                    acc[jj][mm] = fmaf(xp[dd], w[dd][jj], acc[jj][mm]);
        }
    }
#pragma unroll
    for (int jj = 0; jj < 4; ++jj) {
        const int j = jj * 256 + tid;
        const float bv = b1[e * H_ + j];
#pragma unroll
        for (int mm = 0; mm < TM; ++mm) Hs3[mm][j] = fmaxf(acc[jj][mm] + bv, 0.f);
    }
    __syncthreads();
    const float* W2e = W2 + (size_t)e * H_ * D_;
    float acc2[2][TM];
#pragma unroll
    for (int oo = 0; oo < 2; ++oo)
#pragma unroll
        for (int mm = 0; mm < TM; ++mm) acc2[oo][mm] = 0.f;
    for (int j4 = 0; j4 < H_ / 4; ++j4) {
        float w[4][2];
#pragma unroll
        for (int dd = 0; dd < 4; ++dd) {
            const float* wp = W2e + (size_t)(j4 * 4 + dd) * D_ + tid;
#pragma unroll
            for (int oo = 0; oo < 2; ++oo) w[dd][oo] = wp[oo * 256];
        }
#pragma unroll
        for (int mm = 0; mm < TM; ++mm) {
            const float4 hv = ((const float4*)&Hs3[mm][0])[j4];
            const float* hp = &hv.x;
#pragma unroll
            for (int dd = 0; dd < 4; ++dd)
#pragma unroll
                for (int oo = 0; oo < 2; ++oo)
                    acc2[oo][mm] = fmaf(hp[dd], w[dd][oo], acc2[oo][mm]);
        }
    }
#pragma unroll
    for (int oo = 0; oo < 2; ++oo) {
        const int o = oo * 256 + tid;
        const float bv = b2[e * D_ + o];
        for (int mm = 0; mm < mact; ++mm)
            atomicAdd(out + (size_t)tks[mm] * D_ + o, (acc2[oo][mm] + bv) * gs[mm]);
    }
}

// ======================= host launcher =======================

extern "C" void kernel_launch(void* const* d_in, const int* in_sizes, int n_in,
                              void* d_out, int out_size, void* d_ws, size_t ws_size,
                              hipStream_t stream)
{
    const float* x    = (const float*)d_in[0];
    const int*   mask = (const int*)d_in[1];
    const float* wg   = (const float*)d_in[2];
    const float* W1   = (const float*)d_in[3];
    const float* b1   = (const float*)d_in[4];
    const float* W2   = (const float*)d_in[5];
    const float* b2   = (const float*)d_in[6];
    float* out = (float*)d_out;

    char* ws = (char*)d_ws;
    int*   counts = (int*)ws;                       // 32 B
    int*   lists  = (int*)(ws + 256);               // 128 KB
    float* gvals  = (float*)(ws + 256 + 131072);    // 128 KB

    // Tier A layout
    ushort2* tokSlot = (ushort2*)(ws + 0x42000);                        // 16 KB
    uchar2* tokE = (uchar2*)(ws + 0x48000);                             // 8 KB
    float2* tokG = (float2*)(ws + 0x50000);                             // 32 KB
    ushort2* locs = (ushort2*)(ws + 0x58000);                           // 16 KB
    int* blockCnt = (int*)(ws + 0x5C000);                               // 512 B
    unsigned short* xbf  = (unsigned short*)(ws + 0x60000);             // 4 MB
    unsigned short* W1Sa = (unsigned short*)(ws + 0x480000);            // 8 MB
    unsigned short* W2Sa = (unsigned short*)(ws + 0xC80000);            // 8 MB
    unsigned short* Hbuf = (unsigned short*)(ws + 0x1480000);           // 16.5 MB
    unsigned short* Ybuf = (unsigned short*)(ws + 0x2500000);           // 8.25 MB
    const size_t needA2 = 0x2500000 + (size_t)8448 * 512 * 2;           // ~47.1 MB

    const size_t wt_bytes = (size_t)E_ * D_ * H_ * 2;
    const size_t needB = 524288 + 2 * wt_bytes;                         // ~17.3 MB

    if (ws_size >= needA2) {
        prep_fused<<<2048, 256, 0, stream>>>(x, mask, wg, W1, W2,
                                             xbf, tokE, tokG, W1Sa, W2Sa);
        build1_kernel<<<16, 256, 0, stream>>>(tokE, locs, blockCnt);
        build2_kernel<<<16, 256, 0, stream>>>(tokE, tokG, locs, blockCnt,
                                              counts, lists, gvals, tokSlot);
        stage1_kernel<<<MAXTILE * 4 * 8, 256, 0, stream>>>(xbf, W1Sa, b1, counts, lists, Hbuf);
        stage2y_kernel<<<MAXTILE * 2 * 8, 256, 0, stream>>>(Hbuf, W2Sa, b2, counts, Ybuf);
        combine_kernel<<<1024, 256, 0, stream>>>(x, tokE, tokG, tokSlot, Ybuf, out);
    } else if (ws_size >= needB) {
        unsigned short* W1T = (unsigned short*)(ws + 524288);
        unsigned short* W2T = (unsigned short*)(ws + 524288 + wt_bytes);
        hipMemsetAsync(counts, 0, E_ * sizeof(int), stream);
        gating_kernel<<<NT_ / 4, 256, 0, stream>>>(x, mask, wg, counts, lists, gvals);
        init_out_kernel<<<(NT_ * D_) / 4 / 256, 256, 0, stream>>>(x, out);
        transpose_cvt<<<dim3(H_ / 64, D_ / 64, E_), 256, 0, stream>>>(W1, W1T, D_, H_);
        transpose_cvt<<<dim3(D_ / 64, H_ / 64, E_), 256, 0, stream>>>(W2, W2T, H_, D_);
        expert_mfma<<<(NT_ / TM) * E_, 256, 0, stream>>>(x, W1T, b1, W2T, b2,
                                                         counts, lists, gvals, out);
    } else {
        hipMemsetAsync(counts, 0, E_ * sizeof(int), stream);
        gating_kernel<<<NT_ / 4, 256, 0, stream>>>(x, mask, wg, counts, lists, gvals);
        init_out_kernel<<<(NT_ * D_) / 4 / 256, 256, 0, stream>>>(x, out);
        expert_fp32<<<dim3(NT_ / TM, E_), 256, 0, stream>>>(x, W1, b1, W2, b2,
                                                            counts, lists, gvals, out);
    }
}